// Round 6
// baseline (1785.610 us; speedup 1.0000x reference)
//
#include <hip/hip_runtime.h>
#include <hip/hip_fp16.h>

// RaBitQ forward, two kernels.
// x: 262144 vectors of D=128 fp32. P: 128x128 fp32 orthonormal.
// out f32 concat: x_hat[262144*128] | packed[262144*16] | norms16[262144] | x016[262144]
//
// Kernel A (quantize), lane-owns-vector form:
//   lane's x row in 32 float4 VGPRs (loaded once, per-lane);
//   P rows via wave-uniform loads -> s_load (SGPR operand, SMEM pipe);
//   inner loop = pure v_fma with 4 independent e-chains;
//   per-e chain = ascending-d sequential fmaf == round-1/5 PROVEN sign chain;
//   signs/norm/x0 lane-local (no ballot/shuffle/LDS/barrier); stores coalesced.
// Kernel B (dequantize): round-5 kernel VERBATIM (proven, ~38us, write-bound).

#define NVEC_TOTAL (4 * 16 * 4096)

typedef short short8 __attribute__((ext_vector_type(8)));
typedef float f32x4 __attribute__((ext_vector_type(4)));
typedef unsigned int u32x4v __attribute__((ext_vector_type(4)));
typedef unsigned long long ull;

__device__ __forceinline__ unsigned short f2bf(float f) {  // fp32 -> bf16 RNE
  unsigned u = __float_as_uint(f);
  return (unsigned short)((u + 0x7FFFu + ((u >> 16) & 1u)) >> 16);
}

// ========================= Kernel A: quantize =========================
__global__ __launch_bounds__(256, 3) void rabitq_quant(const float* __restrict__ x,
                                                       const float* __restrict__ Pm,
                                                       float* __restrict__ out) {
  const int vec = blockIdx.x * 256 + threadIdx.x;  // my vector (lane-owns-vector)

  float* const out_pack = out + (size_t)NVEC_TOTAL * 128;
  float* const out_norm = out_pack + (size_t)NVEC_TOTAL * 16;
  float* const out_x0   = out_norm + NVEC_TOTAL;

  // ---- load my x row once: 32 float4 = 128 VGPRs, static indices ----
  float4 xr[32];
  {
    const float4* xp = (const float4*)(x + (size_t)vec * 128);
#pragma unroll
    for (int j = 0; j < 32; ++j) xr[j] = xp[j];
  }

  ull m01 = 0ull, m23 = 0ull;  // sign bits e=0..63 / 64..127 (LSB = lowest e)
  float s1 = 0.0f, n2 = 0.0f;

#pragma unroll 1
  for (int eg = 0; eg < 32; ++eg) {
    // 4 rotated coords e = eg*4 + q; P rows wave-uniform -> scalar loads
    const float4* p0 = (const float4*)(Pm + (size_t)(eg * 4 + 0) * 128);
    const float4* p1 = (const float4*)(Pm + (size_t)(eg * 4 + 1) * 128);
    const float4* p2 = (const float4*)(Pm + (size_t)(eg * 4 + 2) * 128);
    const float4* p3 = (const float4*)(Pm + (size_t)(eg * 4 + 3) * 128);

    float a0 = 0.f, a1 = 0.f, a2 = 0.f, a3 = 0.f;
#pragma unroll
    for (int j = 0; j < 32; ++j) {
      const float4 xv = xr[j];
      const float4 q0 = p0[j], q1 = p1[j], q2 = p2[j], q3 = p3[j];
      // ascending-d sequential fmaf chain per e  == proven round-1 chain
      a0 = fmaf(xv.x, q0.x, a0); a0 = fmaf(xv.y, q0.y, a0);
      a0 = fmaf(xv.z, q0.z, a0); a0 = fmaf(xv.w, q0.w, a0);
      a1 = fmaf(xv.x, q1.x, a1); a1 = fmaf(xv.y, q1.y, a1);
      a1 = fmaf(xv.z, q1.z, a1); a1 = fmaf(xv.w, q1.w, a1);
      a2 = fmaf(xv.x, q2.x, a2); a2 = fmaf(xv.y, q2.y, a2);
      a2 = fmaf(xv.z, q2.z, a2); a2 = fmaf(xv.w, q2.w, a2);
      a3 = fmaf(xv.x, q3.x, a3); a3 = fmaf(xv.y, q3.y, a3);
      a3 = fmaf(xv.z, q3.z, a3); a3 = fmaf(xv.w, q3.w, a3);
    }

    // sign nibble for e = eg*4 .. eg*4+3
    const unsigned nib = (a0 >= 0.f ? 1u : 0u) | (a1 >= 0.f ? 2u : 0u) |
                         (a2 >= 0.f ? 4u : 0u) | (a3 >= 0.f ? 8u : 0u);
    if (eg < 16) m01 |= (ull)nib << (eg * 4);
    else         m23 |= (ull)nib << ((eg - 16) * 4);

    // lane-local partial sums, e ascending
    s1 += fabsf(a0); s1 += fabsf(a1); s1 += fabsf(a2); s1 += fabsf(a3);
    n2 = fmaf(a0, a0, n2); n2 = fmaf(a1, a1, n2);
    n2 = fmaf(a2, a2, n2); n2 = fmaf(a3, a3, n2);
  }

  // ---- finalize ----
  const float norm = fmaxf(sqrtf(n2), 1e-8f);
  const float n16  = __half2float(__float2half(norm));
  const float x0   = s1 / (128.0f * norm);
  const float x016 = __half2float(__float2half(x0));
  out_norm[vec] = n16;
  out_x0[vec]   = x016;

  // ---- packed bytes as floats: byte b = bits e=8b..8b+7, LSB first ----
  float4 f0, f1, f2, f3;
  f0.x = (float)((unsigned)(m01 >>  0) & 255u);
  f0.y = (float)((unsigned)(m01 >>  8) & 255u);
  f0.z = (float)((unsigned)(m01 >> 16) & 255u);
  f0.w = (float)((unsigned)(m01 >> 24) & 255u);
  f1.x = (float)((unsigned)(m01 >> 32) & 255u);
  f1.y = (float)((unsigned)(m01 >> 40) & 255u);
  f1.z = (float)((unsigned)(m01 >> 48) & 255u);
  f1.w = (float)((unsigned)(m01 >> 56) & 255u);
  f2.x = (float)((unsigned)(m23 >>  0) & 255u);
  f2.y = (float)((unsigned)(m23 >>  8) & 255u);
  f2.z = (float)((unsigned)(m23 >> 16) & 255u);
  f2.w = (float)((unsigned)(m23 >> 24) & 255u);
  f3.x = (float)((unsigned)(m23 >> 32) & 255u);
  f3.y = (float)((unsigned)(m23 >> 40) & 255u);
  f3.z = (float)((unsigned)(m23 >> 48) & 255u);
  f3.w = (float)((unsigned)(m23 >> 56) & 255u);
  float4* pp = (float4*)(out_pack + (size_t)vec * 16);
  pp[0] = f0; pp[1] = f1; pp[2] = f2; pp[3] = f3;
}

// ========================= Kernel B: dequantize (round-5 VERBATIM) =========================
__global__ __launch_bounds__(256, 4) void rabitq_dequant(const float* __restrict__ Pm,
                                                         float* __restrict__ out) {
  __shared__ __align__(16) unsigned Bp[2048 * 4];  // 32 KiB bf16 B-frags

  const int tid = threadIdx.x, lane = tid & 63, ww = tid >> 6;
  const int l15 = lane & 15, lg = lane >> 4;

#pragma unroll
  for (int i = 0; i < 8; ++i) {
    const int s = tid + i * 256;
    const int ks = s >> 9, n = (s >> 6) & 7, l = s & 63;
    const int kb = ks * 32 + (l >> 4) * 8;
    const int f = n * 16 + (l & 15);
    u32x4v wv;
#pragma unroll
    for (int u = 0; u < 4; ++u) {
      const float p0 = Pm[(size_t)(kb + 2 * u) * 128 + f];
      const float p1 = Pm[(size_t)(kb + 2 * u + 1) * 128 + f];
      wv[u] = (unsigned)f2bf(p0) | ((unsigned)f2bf(p1) << 16);
    }
    *(u32x4v*)(&Bp[s * 4]) = wv;
  }
  __syncthreads();

  const float* const out_pack = out + (size_t)NVEC_TOTAL * 128;
  const float* const out_norm = out_pack + (size_t)NVEC_TOTAL * 16;
  const float* const out_x0   = out_norm + NVEC_TOTAL;

#pragma unroll 1
  for (int t = 0; t < 4; ++t) {
    const int vbase = (blockIdx.x * 4 + ww) * 64 + t * 16;
    const int vec = vbase + l15;

    const float* pb = out_pack + (size_t)vec * 16;
    const float4 b0 = *(const float4*)(pb + 0);
    const float4 b1 = *(const float4*)(pb + 4);
    const float4 b2 = *(const float4*)(pb + 8);
    const float4 b3 = *(const float4*)(pb + 12);
    unsigned mw[4];
    mw[0] = (unsigned)b0.x | ((unsigned)b0.y << 8) | ((unsigned)b0.z << 16) | ((unsigned)b0.w << 24);
    mw[1] = (unsigned)b1.x | ((unsigned)b1.y << 8) | ((unsigned)b1.z << 16) | ((unsigned)b1.w << 24);
    mw[2] = (unsigned)b2.x | ((unsigned)b2.y << 8) | ((unsigned)b2.z << 16) | ((unsigned)b2.w << 24);
    mw[3] = (unsigned)b3.x | ((unsigned)b3.y << 8) | ((unsigned)b3.z << 16) | ((unsigned)b3.w << 24);

    short8 a8[4];
#pragma unroll
    for (int ks = 0; ks < 4; ++ks) {
      const unsigned nb = (~mw[ks]) >> (lg * 8);
      u32x4v ta;
      ta[0] = 0x3F803F80u | ((nb & 1u) << 15)        | ((nb & 2u) << 30);
      ta[1] = 0x3F803F80u | (((nb >> 2) & 1u) << 15) | (((nb >> 2) & 2u) << 30);
      ta[2] = 0x3F803F80u | (((nb >> 4) & 1u) << 15) | (((nb >> 4) & 2u) << 30);
      ta[3] = 0x3F803F80u | (((nb >> 6) & 1u) << 15) | (((nb >> 6) & 2u) << 30);
      a8[ks] = __builtin_bit_cast(short8, ta);
    }

    f32x4 dacc[8];
#pragma unroll
    for (int n = 0; n < 8; ++n) { dacc[n][0] = 0.f; dacc[n][1] = 0.f; dacc[n][2] = 0.f; dacc[n][3] = 0.f; }
#pragma unroll
    for (int n = 0; n < 8; ++n) {
#pragma unroll
      for (int ks = 0; ks < 4; ++ks) {
        const short8 b8 = __builtin_bit_cast(short8, *(const u32x4v*)(&Bp[(ks * 512 + n * 64 + lane) * 4]));
        dacc[n] = __builtin_amdgcn_mfma_f32_16x16x32_bf16(a8[ks], b8, dacc[n], 0, 0, 0);
      }
    }

#pragma unroll
    for (int r = 0; r < 4; ++r) {
      const int row = vbase + lg * 4 + r;
      const float sc = out_norm[row] * out_x0[row];
      float* op = out + (size_t)row * 128 + l15;
#pragma unroll
      for (int n = 0; n < 8; ++n) op[n * 16] = sc * dacc[n][r];
    }
  }
}

extern "C" void kernel_launch(void* const* d_in, const int* in_sizes, int n_in,
                              void* d_out, int out_size, void* d_ws, size_t ws_size,
                              hipStream_t stream) {
  const float* x  = (const float*)d_in[0];
  const float* Pm = (const float*)d_in[1];
  float* out = (float*)d_out;
  // A: 262144 vec / 256 per block = 1024 blocks, exact cover.
  hipLaunchKernelGGL(rabitq_quant, dim3(1024), dim3(256), 0, stream, x, Pm, out);
  // B: 262144 vec / (4 waves * 4 passes * 16 vec) = 1024 blocks, exact cover.
  hipLaunchKernelGGL(rabitq_dequant, dim3(1024), dim3(256), 0, stream, Pm, out);
}

// Round 8
// 242.766 us; speedup vs baseline: 7.3553x; 7.3553x over previous
//
#include <hip/hip_runtime.h>
#include <hip/hip_fp16.h>

// RaBitQ forward, two kernels.
// x: 262144 vectors of D=128 fp32. P: 128x128 fp32 orthonormal.
// out f32 concat: x_hat[262144*128] | packed[262144*16] | norms16[262144] | x016[262144]
//
// Kernel A (quantize): R5 numerics VERBATIM (LDS fp32 P swizzled, ascending-d
//   fmaf chain -> signs bit-identical to proven rounds 1/5). x delivery fixed
//   with standard primitives only (T14 reg-staging):
//     per-lane coalesced float4 global loads (full MLP)
//     -> ds_write_b128 into a wave-private 4 KiB LDS slot
//     -> j-loop reads x as wave-uniform LDS broadcasts (conflict-free).
//   Prefetch next pass's globals right after this pass's ds_writes; all waits
//   compiler-inserted. No barriers after prologue. 1024-thr block, 16 waves,
//   128 KiB LDS (launch proven in R7), 1 block/CU = 4 waves/SIMD.
// Kernel B (dequantize): round-5 kernel VERBATIM (proven, ~38us, write-bound).

#define NVEC_TOTAL (4 * 16 * 4096)
#define ROUNDS 4

typedef short short8 __attribute__((ext_vector_type(8)));
typedef float f32x4 __attribute__((ext_vector_type(4)));
typedef unsigned int u32x4v __attribute__((ext_vector_type(4)));
typedef unsigned long long ull;

__device__ __forceinline__ float rfl_f(float v) {
  return __int_as_float(__builtin_amdgcn_readfirstlane(__float_as_int(v)));
}

__device__ __forceinline__ ull sel8_u64(const ull* a, int s) {
  ull r0 = (s & 1) ? a[1] : a[0];
  ull r1 = (s & 1) ? a[3] : a[2];
  ull r2 = (s & 1) ? a[5] : a[4];
  ull r3 = (s & 1) ? a[7] : a[6];
  ull r4 = (s & 2) ? r1 : r0;
  ull r5 = (s & 2) ? r3 : r2;
  return (s & 4) ? r5 : r4;
}

__device__ __forceinline__ float sel8_f(const float* a, int s) {
  float r0 = (s & 1) ? a[1] : a[0];
  float r1 = (s & 1) ? a[3] : a[2];
  float r2 = (s & 1) ? a[5] : a[4];
  float r3 = (s & 1) ? a[7] : a[6];
  float r4 = (s & 2) ? r1 : r0;
  float r5 = (s & 2) ? r3 : r2;
  return (s & 4) ? r5 : r4;
}

__device__ __forceinline__ unsigned short f2bf(float f) {  // fp32 -> bf16 RNE
  unsigned u = __float_as_uint(f);
  return (unsigned short)((u + 0x7FFFu + ((u >> 16) & 1u)) >> 16);
}

// ========================= Kernel A: quantize =========================
__global__ __launch_bounds__(1024, 4) void rabitq_quant(const float* __restrict__ x,
                                                        const float* __restrict__ Pm,
                                                        float* __restrict__ out) {
  extern __shared__ __align__(16) char smem[];
  float* const Pl = (float*)smem;     // 64 KiB swizzled fp32 P
  char* const xs = smem + 65536;      // 16 wave-slots x 4 KiB

  const int tid = threadIdx.x;
  const int lane = tid & 63;
  const int ww = tid >> 6;

  // ---- stage P into LDS, swizzled (16B blocks, j ^ (row&7)) ----
  {
    const int r = tid >> 3;        // row 0..127, eight threads per row
    const int q = tid & 7;
#pragma unroll
    for (int c = 0; c < 4; ++c) {
      const int dd = q * 16 + c * 4;
      const int sj = (((dd >> 2) ^ (r & 7)) << 2);
      const float4 v = *(const float4*)(Pm + (size_t)r * 128 + dd);
      *(float4*)(&Pl[r * 128 + sj]) = v;
    }
  }
  __syncthreads();

  const int w = blockIdx.x * 16 + ww;  // global wave id, 0..8191
  float* const out_pack = out + (size_t)NVEC_TOTAL * 128;
  float* const out_norm = out_pack + (size_t)NVEC_TOTAL * 16;
  float* const out_x0   = out_norm + NVEC_TOTAL;

  const int sw1 = lane & 7;            // row-swizzle key
  float* const xb = (float*)(xs + ww * 4096);  // wave-private slot [8 vec][128 f]
  const int lsub = (lane >> 5);        // which of the 2 vectors per issue
  const int lcol = (lane & 31) * 4;    // float offset within vector

  // ---- prologue: load pass-0 x into regs (per-lane, coalesced) ----
  float4 pf0, pf1, pf2, pf3;
  {
    const int vb = w * 32;
    pf0 = *(const float4*)(x + (size_t)(vb + 0 + lsub) * 128 + lcol);
    pf1 = *(const float4*)(x + (size_t)(vb + 2 + lsub) * 128 + lcol);
    pf2 = *(const float4*)(x + (size_t)(vb + 4 + lsub) * 128 + lcol);
    pf3 = *(const float4*)(x + (size_t)(vb + 6 + lsub) * 128 + lcol);
  }

#pragma unroll 1
  for (int t = 0; t < ROUNDS; ++t) {
    const int vbase = w * 32 + t * 8;

    // ---- write staged regs to wave slot (canonical b128 pattern) ----
    {
      char* const dst = (char*)xb + lane * 16;
      *(float4*)(dst + 0)    = pf0;
      *(float4*)(dst + 1024) = pf1;
      *(float4*)(dst + 2048) = pf2;
      *(float4*)(dst + 3072) = pf3;
    }

    // ---- prefetch next pass's x into regs (latency hides under compute) ----
    if (t + 1 < ROUNDS) {
      const int vb = w * 32 + (t + 1) * 8;
      pf0 = *(const float4*)(x + (size_t)(vb + 0 + lsub) * 128 + lcol);
      pf1 = *(const float4*)(x + (size_t)(vb + 2 + lsub) * 128 + lcol);
      pf2 = *(const float4*)(x + (size_t)(vb + 4 + lsub) * 128 + lcol);
      pf3 = *(const float4*)(x + (size_t)(vb + 6 + lsub) * 128 + lcol);
    }

    // ---- x_rot = x @ P^T : R5-verbatim chain (signs proven vs np) ----
    float acc_lo[8], acc_hi[8];
#pragma unroll
    for (int v = 0; v < 8; ++v) { acc_lo[v] = 0.f; acc_hi[v] = 0.f; }

#pragma unroll 2
    for (int j = 0; j < 32; ++j) {
      const int js = ((j ^ sw1) << 2);
      const float4 pl = *(const float4*)(&Pl[lane * 128 + js]);
      const float4 ph = *(const float4*)(&Pl[(lane + 64) * 128 + js]);
#pragma unroll
      for (int v = 0; v < 8; ++v) {
        // wave-uniform LDS address -> broadcast, conflict-free
        const float4 xv = *(const float4*)(xb + v * 128 + j * 4);
        float al = acc_lo[v], ah = acc_hi[v];
        al = fmaf(xv.x, pl.x, al); ah = fmaf(xv.x, ph.x, ah);
        al = fmaf(xv.y, pl.y, al); ah = fmaf(xv.y, ph.y, ah);
        al = fmaf(xv.z, pl.z, al); ah = fmaf(xv.z, ph.z, ah);
        al = fmaf(xv.w, pl.w, al); ah = fmaf(xv.w, ph.w, ah);
        acc_lo[v] = al; acc_hi[v] = ah;
      }
    }

    // ---- signs, norm, x0 : R5 VERBATIM ----
    ull bl[8], bh[8];
    float n16v[8], x0v[8];
#pragma unroll
    for (int v = 0; v < 8; ++v) {
      bl[v] = __ballot(acc_lo[v] >= 0.0f);
      bh[v] = __ballot(acc_hi[v] >= 0.0f);
      const float a1 = fabsf(acc_lo[v]);
      const float a2 = fabsf(acc_hi[v]);
      float s1 = a1 + a2;
      float n2 = fmaf(a1, a1, a2 * a2);
#pragma unroll
      for (int off = 32; off > 0; off >>= 1) {
        s1 += __shfl_xor(s1, off);
        n2 += __shfl_xor(n2, off);
      }
      float norm = fmaxf(sqrtf(n2), 1e-8f);
      const float n16  = __half2float(__float2half(norm));
      const float x0   = s1 / (128.0f * norm);
      const float x016 = __half2float(__float2half(x0));
      n16v[v] = rfl_f(n16);
      x0v[v]  = rfl_f(x016);
    }

    // ---- store packed bytes / norms16 / x016 : R5 VERBATIM ----
    {
      const int s = lane & 7;
      const int jb = lane >> 3;
      const ull el = sel8_u64(bl, s);
      const ull eh = sel8_u64(bh, s);
      const float fl = (float)((unsigned)(el >> (8 * jb)) & 255u);
      const float fh = (float)((unsigned)(eh >> (8 * jb)) & 255u);
      out_pack[(size_t)(vbase + s) * 16 + jb] = fl;
      out_pack[(size_t)(vbase + s) * 16 + 8 + jb] = fh;
      if (lane < 16) {
        const float nsel = sel8_f(n16v, s);
        const float xsel = sel8_f(x0v, s);
        if (lane < 8) out_norm[vbase + s] = nsel;
        else          out_x0[vbase + s] = xsel;
      }
    }
  }
}

// ========================= Kernel B: dequantize (round-5 VERBATIM) =========================
__global__ __launch_bounds__(256, 4) void rabitq_dequant(const float* __restrict__ Pm,
                                                         float* __restrict__ out) {
  __shared__ __align__(16) unsigned Bp[2048 * 4];  // 32 KiB bf16 B-frags

  const int tid = threadIdx.x, lane = tid & 63, ww = tid >> 6;
  const int l15 = lane & 15, lg = lane >> 4;

#pragma unroll
  for (int i = 0; i < 8; ++i) {
    const int s = tid + i * 256;
    const int ks = s >> 9, n = (s >> 6) & 7, l = s & 63;
    const int kb = ks * 32 + (l >> 4) * 8;
    const int f = n * 16 + (l & 15);
    u32x4v wv;
#pragma unroll
    for (int u = 0; u < 4; ++u) {
      const float p0 = Pm[(size_t)(kb + 2 * u) * 128 + f];
      const float p1 = Pm[(size_t)(kb + 2 * u + 1) * 128 + f];
      wv[u] = (unsigned)f2bf(p0) | ((unsigned)f2bf(p1) << 16);
    }
    *(u32x4v*)(&Bp[s * 4]) = wv;
  }
  __syncthreads();

  const float* const out_pack = out + (size_t)NVEC_TOTAL * 128;
  const float* const out_norm = out_pack + (size_t)NVEC_TOTAL * 16;
  const float* const out_x0   = out_norm + NVEC_TOTAL;

#pragma unroll 1
  for (int t = 0; t < 4; ++t) {
    const int vbase = (blockIdx.x * 4 + ww) * 64 + t * 16;
    const int vec = vbase + l15;

    const float* pb = out_pack + (size_t)vec * 16;
    const float4 b0 = *(const float4*)(pb + 0);
    const float4 b1 = *(const float4*)(pb + 4);
    const float4 b2 = *(const float4*)(pb + 8);
    const float4 b3 = *(const float4*)(pb + 12);
    unsigned mw[4];
    mw[0] = (unsigned)b0.x | ((unsigned)b0.y << 8) | ((unsigned)b0.z << 16) | ((unsigned)b0.w << 24);
    mw[1] = (unsigned)b1.x | ((unsigned)b1.y << 8) | ((unsigned)b1.z << 16) | ((unsigned)b1.w << 24);
    mw[2] = (unsigned)b2.x | ((unsigned)b2.y << 8) | ((unsigned)b2.z << 16) | ((unsigned)b2.w << 24);
    mw[3] = (unsigned)b3.x | ((unsigned)b3.y << 8) | ((unsigned)b3.z << 16) | ((unsigned)b3.w << 24);

    short8 a8[4];
#pragma unroll
    for (int ks = 0; ks < 4; ++ks) {
      const unsigned nb = (~mw[ks]) >> (lg * 8);
      u32x4v ta;
      ta[0] = 0x3F803F80u | ((nb & 1u) << 15)        | ((nb & 2u) << 30);
      ta[1] = 0x3F803F80u | (((nb >> 2) & 1u) << 15) | (((nb >> 2) & 2u) << 30);
      ta[2] = 0x3F803F80u | (((nb >> 4) & 1u) << 15) | (((nb >> 4) & 2u) << 30);
      ta[3] = 0x3F803F80u | (((nb >> 6) & 1u) << 15) | (((nb >> 6) & 2u) << 30);
      a8[ks] = __builtin_bit_cast(short8, ta);
    }

    f32x4 dacc[8];
#pragma unroll
    for (int n = 0; n < 8; ++n) { dacc[n][0] = 0.f; dacc[n][1] = 0.f; dacc[n][2] = 0.f; dacc[n][3] = 0.f; }
#pragma unroll
    for (int n = 0; n < 8; ++n) {
#pragma unroll
      for (int ks = 0; ks < 4; ++ks) {
        const short8 b8 = __builtin_bit_cast(short8, *(const u32x4v*)(&Bp[(ks * 512 + n * 64 + lane) * 4]));
        dacc[n] = __builtin_amdgcn_mfma_f32_16x16x32_bf16(a8[ks], b8, dacc[n], 0, 0, 0);
      }
    }

#pragma unroll
    for (int r = 0; r < 4; ++r) {
      const int row = vbase + lg * 4 + r;
      const float sc = out_norm[row] * out_x0[row];
      float* op = out + (size_t)row * 128 + l15;
#pragma unroll
      for (int n = 0; n < 8; ++n) op[n * 16] = sc * dacc[n][r];
    }
  }
}

extern "C" void kernel_launch(void* const* d_in, const int* in_sizes, int n_in,
                              void* d_out, int out_size, void* d_ws, size_t ws_size,
                              hipStream_t stream) {
  const float* x  = (const float*)d_in[0];
  const float* Pm = (const float*)d_in[1];
  float* out = (float*)d_out;
  // A: 262144 vec / (16 waves * 4 rounds * 8 vec) = 512 blocks, exact cover.
  // Dynamic LDS: 64 KiB P + 16 waves * 4 KiB x = 128 KiB (launch proven in R7).
  hipLaunchKernelGGL(rabitq_quant, dim3(512), dim3(1024), 131072, stream, x, Pm, out);
  // B: 262144 vec / (4 waves * 4 passes * 16 vec) = 1024 blocks, exact cover.
  hipLaunchKernelGGL(rabitq_dequant, dim3(1024), dim3(256), 0, stream, Pm, out);
}